// Round 10
// baseline (69.999 us; speedup 1.0000x reference)
//
#include <hip/hip_runtime.h>
#include <math.h>

// Dims (fixed per reference)
#define B   128
#define L   50
#define V   100000
#define ND  4
#define D   64

// out layout: P_v (B*V) | infomax_loss (1) | gnn (B*ND*L*D)

__device__ __forceinline__ float log_sigmoid(float x) {
    if (x >= 0.f) return -log1pf(expf(-x));
    return x - log1pf(expf(x));
}

// K0: gnn broadcast-write, full-GPU wide. One float4 per thread.
// gnn[b][n][l][d] = emb_i[nodes[b][l]][d]  (n = 0..3 broadcast)
// B*ND*L*(D/4) = 409600 float4s -> 1600 blocks x 256.
__global__ __launch_bounds__(256) void k0_gnn(
    const int* __restrict__ nodes, const float* __restrict__ emb_i,
    float* __restrict__ gnn)
{
    const int idx = blockIdx.x * 256 + threadIdx.x;   // float4 index
    const int d4   = idx & (D / 4 - 1);               // 0..15
    const int rest = idx >> 4;                        // b*ND*L + n*L + l
    const int l    = rest % L;
    const int bn   = rest / L;
    const int b    = bn >> 2;
    const int node = nodes[b * L + l];
    const float4 val = reinterpret_cast<const float4*>(emb_i)[node * (D / 4) + d4];
    reinterpret_cast<float4*>(gnn)[idx] = val;
}

// K1: per-b (64 threads = 1 wave, t == d): masked-mean gr, last row,
// u = W_im@gr, h = tanh([gr|last]@W_pvsd + b). Also zero-inits loss.
__global__ __launch_bounds__(64) void k1_small(
    const int* __restrict__ nodes, const int* __restrict__ mask,
    const int* __restrict__ sli, const float* __restrict__ emb_i,
    const float* __restrict__ W_pvsd, const float* __restrict__ b_pvsd,
    const float* __restrict__ W_im,
    float* __restrict__ u, float* __restrict__ h, float* __restrict__ loss)
{
    const int b = blockIdx.x;
    const int t = threadIdx.x;     // = d
    if (b == 0 && t == 0) loss[0] = 0.f;
    __shared__ int   s_nodes[L];
    __shared__ float s_mask[L];
    __shared__ float s_gr[D], s_last[D];
    if (t < L) {
        s_nodes[t] = nodes[b * L + t];
        s_mask[t]  = (float)mask[b * L + t];
    }
    __syncthreads();
    float msum = 0.f, acc = 0.f;
    for (int l = 0; l < L; ++l) {
        float m = s_mask[l];
        msum += m;
        acc  += m * emb_i[(size_t)s_nodes[l] * D + t];
    }
    s_gr[t]   = acc / msum;
    s_last[t] = emb_i[(size_t)s_nodes[sli[b]] * D + t];
    __syncthreads();
    float uu = 0.f;
    #pragma unroll
    for (int e = 0; e < D; ++e) uu += W_im[t * D + e] * s_gr[e];
    u[b * D + t] = uu;
    float pre = b_pvsd[t];
    #pragma unroll
    for (int k = 0; k < D; ++k) pre += s_gr[k]   * W_pvsd[k * D + t];
    #pragma unroll
    for (int k = 0; k < D; ++k) pre += s_last[k] * W_pvsd[(D + k) * D + t];
    h[b * D + t] = tanhf(pre);
}

// K3: infomax partials per b, accumulated into the scalar loss.
__global__ __launch_bounds__(64) void k3_infomax(
    const float* __restrict__ u, const float* __restrict__ gnn,
    float* __restrict__ loss)
{
    const int b = blockIdx.x;
    const int t = threadIdx.x;
    __shared__ float s_up[D], s_un[D];
    const int bm1 = (b + B - 1) % B;
    s_up[t] = u[b * D + t];
    s_un[t] = u[bm1 * D + t];
    __syncthreads();
    float lsp = 0.f, lsn = 0.f;
    if (t < L) {
        const float* se = gnn + ((size_t)(b * ND) * L + t) * D;  // n=0 copy
        float sp = 0.f, sn = 0.f;
        #pragma unroll
        for (int d2 = 0; d2 < D; ++d2) {
            float vv = se[d2];
            sp += vv * s_up[d2];
            sn += vv * s_un[d2];
        }
        lsp = log_sigmoid(sp);
        lsn = log_sigmoid(-sn);
    }
    float tot = lsp + lsn;
    for (int off = 32; off > 0; off >>= 1) tot += __shfl_down(tot, off);
    if (t == 0) atomicAdd(loss, -tot / (float)(B * L));
}

// K5: P_v[b,v] = h[b] . emb_i[v]
// R9 post-mortem: line-granular consumption fixed the traffic (FETCH
// 394->51MB) but 1564 blocks = 6.1/CU left occupancy at 28% -> latency-
// bound at 41% VALUBusy. Fix: NBSPLIT=8 (3128 blocks ~ 12/CU, saturates
// the 8-block/CU cap). NB=16 accs + 16 pinned line floats ~ 44 VGPR ->
// 8 waves/SIMD. by-fastest ordering keeps the 8 b-slices of a v-tile
// concurrent so L2/L3 absorb the cross-slice emb refetch.
#define NBSPLIT 8
#define NB (B / NBSPLIT)   // 16 b per thread
__global__ __launch_bounds__(256) void k5_pv(
    const float* __restrict__ h, const float* __restrict__ emb_i,
    float* __restrict__ pv)
{
    const int bx = blockIdx.x >> 3;
    const int by = blockIdx.x & 7;
    const int v  = bx * 256 + threadIdx.x;
    const int b0 = by * NB;
    const bool active = (v < V);
    const int vc = active ? v : (V - 1);
    const float4* r4 = reinterpret_cast<const float4*>(emb_i + (size_t)vc * D);
    const float4* h4 = reinterpret_cast<const float4*>(h) + (size_t)b0 * (D / 4);

    float acc[NB];
    #pragma unroll
    for (int j = 0; j < NB; ++j) acc[j] = 0.f;

    #pragma unroll
    for (int KB = 0; KB < 4; ++KB) {
        float4 q0 = r4[4 * KB + 0];
        float4 q1 = r4[4 * KB + 1];
        float4 q2 = r4[4 * KB + 2];
        float4 q3 = r4[4 * KB + 3];
        // Pin the 64B line in VGPRs: loads complete here, cannot be sunk
        // into (or re-issued inside) the j-loop (R4/R5 pathology).
        asm volatile("" : "+v"(q0.x), "+v"(q0.y), "+v"(q0.z), "+v"(q0.w),
                          "+v"(q1.x), "+v"(q1.y), "+v"(q1.z), "+v"(q1.w),
                          "+v"(q2.x), "+v"(q2.y), "+v"(q2.z), "+v"(q2.w),
                          "+v"(q3.x), "+v"(q3.y), "+v"(q3.z), "+v"(q3.w));
        #pragma unroll
        for (int j = 0; j < NB; ++j) {
            const float4* hj = h4 + (size_t)j * (D / 4) + 4 * KB;
            float4 h0 = hj[0], h1 = hj[1], h2 = hj[2], h3 = hj[3]; // s_loads
            float a = acc[j];
            a += q0.x * h0.x; a += q0.y * h0.y; a += q0.z * h0.z; a += q0.w * h0.w;
            a += q1.x * h1.x; a += q1.y * h1.y; a += q1.z * h1.z; a += q1.w * h1.w;
            a += q2.x * h2.x; a += q2.y * h2.y; a += q2.z * h2.z; a += q2.w * h2.w;
            a += q3.x * h3.x; a += q3.y * h3.y; a += q3.z * h3.z; a += q3.w * h3.w;
            acc[j] = a;
        }
    }
    if (active) {
        #pragma unroll
        for (int j = 0; j < NB; ++j)
            pv[(size_t)(b0 + j) * V + v] = acc[j];
    }
}

extern "C" void kernel_launch(void* const* d_in, const int* in_sizes, int n_in,
                              void* d_out, int out_size, void* d_ws, size_t ws_size,
                              hipStream_t stream)
{
    const int*   nodes  = (const int*)d_in[0];
    const int*   sli    = (const int*)d_in[4];
    const int*   mask   = (const int*)d_in[6];
    const float* emb_i  = (const float*)d_in[7];
    const float* W_pvsd = (const float*)d_in[13];
    const float* b_pvsd = (const float*)d_in[14];
    const float* W_im   = (const float*)d_in[15];

    float* pv   = (float*)d_out;               // B*V
    float* loss = pv + (size_t)B * V;          // 1
    float* gnn  = loss + 1;                    // B*ND*L*D

    float* ws = (float*)d_ws;
    float* u  = ws;                            // B*D
    float* h  = u + B * D;                     // B*D

    k0_gnn<<<(B * ND * L * (D / 4)) / 256, 256, 0, stream>>>(nodes, emb_i, gnn);
    k1_small<<<B, 64, 0, stream>>>(nodes, mask, sli, emb_i, W_pvsd, b_pvsd,
                                   W_im, u, h, loss);
    k3_infomax<<<B, 64, 0, stream>>>(u, gnn, loss);
    k5_pv<<<((V + 255) / 256) * NBSPLIT, 256, 0, stream>>>(h, emb_i, pv);
}